// Round 1
// baseline (561.197 us; speedup 1.0000x reference)
//
#include <hip/hip_runtime.h>
#include <hip/hip_bf16.h>
#include <math.h>

// SwinDiT window attention, fused per-window kernel for gfx950.
// Requires ws_size >= ~700 KB (weights bf16 + rpb tables).

#define NW_ 256

typedef __bf16 bf16_t;
typedef __bf16 bf16x8 __attribute__((ext_vector_type(8)));
typedef float f32x4 __attribute__((ext_vector_type(4)));

// ---------------- prep kernels ----------------

__global__ void prep_weights_k(const float* __restrict__ wq, const float* __restrict__ wk,
                               const float* __restrict__ wv, const float* __restrict__ wo,
                               bf16_t* __restrict__ wqkvT, bf16_t* __restrict__ woT) {
  int gid = blockIdx.x * 256 + threadIdx.x;   // 4 * 65536
  int mat = gid >> 16;
  int rc = gid & 65535;
  int r = rc >> 8, c = rc & 255;              // r = out col, c = in row
  const float* src = (mat == 0) ? wq : (mat == 1) ? wk : (mat == 2) ? wv : wo;
  float v = src[c * 256 + r];                 // W[in][out] -> WT[out][in]
  if (mat < 3) wqkvT[gid] = (bf16_t)v;
  else         woT[rc] = (bf16_t)v;
}

__global__ void prep_cpb_bias_k(const float* __restrict__ w1, const float* __restrict__ b1,
                                const float* __restrict__ w2, float* __restrict__ bias_out) {
  __shared__ float hl[512];
  __shared__ float part[256];
  int r = blockIdx.x, tid = threadIdx.x;
  int i = r / 15, j = r % 15;
  float t0 = (float)(i - 7) * (8.0f / 7.0f);
  float t1 = (float)(j - 7) * (8.0f / 7.0f);
  float s0 = (t0 > 0.f) ? 1.f : (t0 < 0.f ? -1.f : 0.f);
  float s1 = (t1 > 0.f) ? 1.f : (t1 < 0.f ? -1.f : 0.f);
  float c0 = s0 * log2f(fabsf(t0) + 1.f) * (1.f / 3.f);
  float c1 = s1 * log2f(fabsf(t1) + 1.f) * (1.f / 3.f);
  for (int c = tid; c < 512; c += 256)
    hl[c] = fmaxf(0.f, c0 * w1[c] + c1 * w1[512 + c] + b1[c]);
  __syncthreads();
  int h = tid & 7, seg = tid >> 3;
  float s = 0.f;
  for (int c = seg * 16; c < seg * 16 + 16; ++c) s += hl[c] * w2[c * 8 + h];
  part[tid] = s;
  __syncthreads();
  if (tid < 8) {
    float acc = 0.f;
    for (int sg = 0; sg < 32; ++sg) acc += part[sg * 8 + tid];
    bias_out[r * 8 + tid] = acc;
  }
}

__global__ void prep_rpb_k(const float* __restrict__ bias, float* __restrict__ rpbT) {
  int gid = blockIdx.x * 256 + threadIdx.x;   // 8*64*64, layout rpbT[h][n][m]
  int h = gid >> 12;
  int nm = gid & 4095;
  int n = nm >> 6, m = nm & 63;
  int dy = (m >> 3) - (n >> 3) + 7;
  int dx = (m & 7) - (n & 7) + 7;
  float v = bias[(dy * 15 + dx) * 8 + h];
  rpbT[gid] = 16.f / (1.f + __expf(-v));
}

// ---------------- fused attention kernel ----------------
// block = 512 threads (8 waves, one head each), grid = 4096 windows.

__global__ __launch_bounds__(512, 2) void swin_attn_k(
    const float* __restrict__ hidden,
    const float* __restrict__ mask,
    const float* __restrict__ bq,
    const float* __restrict__ bv,
    const float* __restrict__ lsc,
    const float* __restrict__ bo,
    const bf16_t* __restrict__ wqkvT,
    const bf16_t* __restrict__ woT,
    const float* __restrict__ rpbT,
    float* __restrict__ out) {
  // Xs: X (later ctx) [64 m][256 k] bf16, chunk-XOR swizzle: elem(m,k) at
  //     m*256 + ((k>>3)^(m&7))*8 + (k&7)
  __shared__ bf16_t Xs[64 * 256];        // 32 KB
  // per head: Q[64 m][32 d] (swz ^(m&3)), K same, V stored as V^T[32 d][64 n] (swz ^(d&7)).
  // P[64 m][64 n] (swz ^(m&7)) overlays Q+K.
  __shared__ bf16_t HB[8][3 * 2048];     // 96 KB
  __shared__ float Ms[64 * 65];          // mask^T [n][m], padded. 16.25 KB

  const int tid = threadIdx.x;
  const int w = blockIdx.x;
  const int lane = tid & 63;
  const int h = tid >> 6;
  const int r15 = lane & 15;
  const int c16 = lane >> 4;

  const float* hw = hidden + (size_t)w * (64 * 256);

  // ---- phase 0: stage X (bf16, swizzled) + mask^T ----
#pragma unroll
  for (int it = 0; it < 4; ++it) {
    int ci = tid + it * 512;           // 2048 16B-chunks
    int m = ci >> 5, ch = ci & 31;
    float4 v0 = ((const float4*)hw)[m * 64 + ch * 2];
    float4 v1 = ((const float4*)hw)[m * 64 + ch * 2 + 1];
    union { bf16_t b[8]; uint4 u; } pk;
    pk.b[0] = (bf16_t)v0.x; pk.b[1] = (bf16_t)v0.y; pk.b[2] = (bf16_t)v0.z; pk.b[3] = (bf16_t)v0.w;
    pk.b[4] = (bf16_t)v1.x; pk.b[5] = (bf16_t)v1.y; pk.b[6] = (bf16_t)v1.z; pk.b[7] = (bf16_t)v1.w;
    *(uint4*)&Xs[m * 256 + ((ch ^ (m & 7)) << 3)] = pk.u;
  }
  {
    const float* mw = mask + (size_t)(w & (NW_ - 1)) * 4096;
#pragma unroll
    for (int it = 0; it < 2; ++it) {
      int f = tid + it * 512;
      int m = f >> 4, n0 = (f & 15) << 2;
      float4 v = ((const float4*)mw)[f];
      Ms[(n0 + 0) * 65 + m] = v.x;
      Ms[(n0 + 1) * 65 + m] = v.y;
      Ms[(n0 + 2) * 65 + m] = v.z;
      Ms[(n0 + 3) * 65 + m] = v.w;
    }
  }
  __syncthreads();

  bf16_t* Qsh = &HB[h][0];
  bf16_t* Ksh = &HB[h][2048];
  bf16_t* Vsh = &HB[h][4096];
  bf16_t* Psh = Qsh;  // P overlays Q+K (read fully before overwrite, in-wave DS order)

  const f32x4 zero4 = {0.f, 0.f, 0.f, 0.f};

  // ---- phase 1: QKV projection, transposed (D[d][m]) ----
  const bf16_t* wqp = wqkvT + (0 * 256 + h * 32) * 256;
  const bf16_t* wkp = wqkvT + (1 * 256 + h * 32) * 256;
  const bf16_t* wvp = wqkvT + (2 * 256 + h * 32) * 256;

  f32x4 accq[2][4], acck[2][4], accv[2][4];
#pragma unroll
  for (int di = 0; di < 2; ++di)
#pragma unroll
    for (int mj = 0; mj < 4; ++mj) { accq[di][mj] = zero4; acck[di][mj] = zero4; accv[di][mj] = zero4; }

#pragma unroll
  for (int ks = 0; ks < 8; ++ks) {
    bf16x8 bx[4];
#pragma unroll
    for (int mj = 0; mj < 4; ++mj) {
      int m = mj * 16 + r15;
      bx[mj] = *(const bf16x8*)&Xs[m * 256 + (((ks * 4 + c16) ^ (m & 7)) << 3)];
    }
#pragma unroll
    for (int di = 0; di < 2; ++di) {
      int woff = (di * 16 + r15) * 256 + ks * 32 + c16 * 8;
      bf16x8 aq = *(const bf16x8*)&wqp[woff];
      bf16x8 ak = *(const bf16x8*)&wkp[woff];
      bf16x8 av = *(const bf16x8*)&wvp[woff];
#pragma unroll
      for (int mj = 0; mj < 4; ++mj) {
        accq[di][mj] = __builtin_amdgcn_mfma_f32_16x16x32_bf16(aq, bx[mj], accq[di][mj], 0, 0, 0);
        acck[di][mj] = __builtin_amdgcn_mfma_f32_16x16x32_bf16(ak, bx[mj], acck[di][mj], 0, 0, 0);
        accv[di][mj] = __builtin_amdgcn_mfma_f32_16x16x32_bf16(av, bx[mj], accv[di][mj], 0, 0, 0);
      }
    }
  }

  // epilogue: bias, cosine-normalize (fp32), fold logit scale into Q, write LDS
  f32x4 bqf[2], bvf[2];
#pragma unroll
  for (int di = 0; di < 2; ++di) {
    bqf[di] = *(const f32x4*)&bq[h * 32 + di * 16 + c16 * 4];
    bvf[di] = *(const f32x4*)&bv[h * 32 + di * 16 + c16 * 4];
  }
  float scale = expf(fminf(lsc[h], 4.6051701859880914f));  // exp(min(ls, ln 100))

#pragma unroll
  for (int mj = 0; mj < 4; ++mj) {
    int m = mj * 16 + r15;
    {  // Q: bias + normalize*scale
      float q[2][4];
      float ss = 0.f;
#pragma unroll
      for (int di = 0; di < 2; ++di)
#pragma unroll
        for (int rg = 0; rg < 4; ++rg) {
          float t = accq[di][mj][rg] + bqf[di][rg];
          q[di][rg] = t;
          ss += t * t;
        }
      ss += __shfl_xor(ss, 16);
      ss += __shfl_xor(ss, 32);
      float rq = scale / fmaxf(sqrtf(ss), 1e-12f);
#pragma unroll
      for (int di = 0; di < 2; ++di) {
        union { bf16_t b[4]; uint2 u; } pk;
#pragma unroll
        for (int rg = 0; rg < 4; ++rg) pk.b[rg] = (bf16_t)(q[di][rg] * rq);
        *(uint2*)&Qsh[m * 32 + (((di * 2 + (c16 >> 1)) ^ (m & 3)) << 3) + ((c16 & 1) << 2)] = pk.u;
      }
    }
    {  // K: normalize (no bias)
      float ss = 0.f;
#pragma unroll
      for (int di = 0; di < 2; ++di)
#pragma unroll
        for (int rg = 0; rg < 4; ++rg) { float t = acck[di][mj][rg]; ss += t * t; }
      ss += __shfl_xor(ss, 16);
      ss += __shfl_xor(ss, 32);
      float rk = 1.f / fmaxf(sqrtf(ss), 1e-12f);
#pragma unroll
      for (int di = 0; di < 2; ++di) {
        union { bf16_t b[4]; uint2 u; } pk;
#pragma unroll
        for (int rg = 0; rg < 4; ++rg) pk.b[rg] = (bf16_t)(acck[di][mj][rg] * rk);
        *(uint2*)&Ksh[m * 32 + (((di * 2 + (c16 >> 1)) ^ (m & 3)) << 3) + ((c16 & 1) << 2)] = pk.u;
      }
    }
    {  // V: bias, store transposed V^T[d][n=m]
#pragma unroll
      for (int di = 0; di < 2; ++di)
#pragma unroll
        for (int rg = 0; rg < 4; ++rg) {
          float t = accv[di][mj][rg] + bvf[di][rg];
          int d = di * 16 + c16 * 4 + rg;
          Vsh[d * 64 + ((((m >> 3) ^ (d & 7))) << 3) + (m & 7)] = (bf16_t)t;
        }
    }
  }
  __syncthreads();  // all waves done reading Xs (it becomes ctx buffer later)

  const int r3 = r15 & 3;
  const int r7 = r15 & 7;

  // ---- phase 2: S^T = Kn * Qn^T (D[n][m]), + rpb + mask, softmax over n ----
  bf16x8 afk[4], bfq[4];
#pragma unroll
  for (int tt = 0; tt < 4; ++tt) {
    afk[tt] = *(const bf16x8*)&Ksh[(tt * 16 + r15) * 32 + ((c16 ^ r3) << 3)];
    bfq[tt] = *(const bf16x8*)&Qsh[(tt * 16 + r15) * 32 + ((c16 ^ r3) << 3)];
  }
  f32x4 accs[4][4];
#pragma unroll
  for (int ti = 0; ti < 4; ++ti)
#pragma unroll
    for (int tj = 0; tj < 4; ++tj)
      accs[ti][tj] = __builtin_amdgcn_mfma_f32_16x16x32_bf16(afk[ti], bfq[tj], zero4, 0, 0, 0);

  const float* rpbh = rpbT + h * 4096;
#pragma unroll
  for (int ti = 0; ti < 4; ++ti) {
#pragma unroll
    for (int rg = 0; rg < 4; ++rg) {
      int n = ti * 16 + c16 * 4 + rg;
#pragma unroll
      for (int tj = 0; tj < 4; ++tj) {
        int m = tj * 16 + r15;
        accs[ti][tj][rg] += rpbh[n * 64 + m] + Ms[n * 65 + m];
      }
    }
  }
  float sminv[4];
#pragma unroll
  for (int tj = 0; tj < 4; ++tj) {
    float v = -3.0e38f;
#pragma unroll
    for (int ti = 0; ti < 4; ++ti)
#pragma unroll
      for (int rg = 0; rg < 4; ++rg) v = fmaxf(v, accs[ti][tj][rg]);
    v = fmaxf(v, __shfl_xor(v, 16));
    v = fmaxf(v, __shfl_xor(v, 32));
    float s = 0.f;
#pragma unroll
    for (int ti = 0; ti < 4; ++ti)
#pragma unroll
      for (int rg = 0; rg < 4; ++rg) {
        float e = __expf(accs[ti][tj][rg] - v);
        accs[ti][tj][rg] = e;
        s += e;
      }
    s += __shfl_xor(s, 16);
    s += __shfl_xor(s, 32);
    sminv[tj] = 1.f / s;
  }
  // write P[m][n] (overlays Q,K - all reads above feed accs, so DS order is safe)
#pragma unroll
  for (int ti = 0; ti < 4; ++ti)
#pragma unroll
    for (int tj = 0; tj < 4; ++tj) {
      union { bf16_t b[4]; uint2 u; } pk;
#pragma unroll
      for (int rg = 0; rg < 4; ++rg) pk.b[rg] = (bf16_t)(accs[ti][tj][rg] * sminv[tj]);
      int m = tj * 16 + r15;
      *(uint2*)&Psh[m * 64 + (((ti * 2 + (c16 >> 1)) ^ (m & 7)) << 3) + ((c16 & 1) << 2)] = pk.u;
    }

  // ---- phase 3: ctx^T = V^T * P^T (D[d][m]) ----
  f32x4 accc[2][4];
#pragma unroll
  for (int di = 0; di < 2; ++di)
#pragma unroll
    for (int mj = 0; mj < 4; ++mj) accc[di][mj] = zero4;
#pragma unroll
  for (int ks = 0; ks < 2; ++ks) {
    bf16x8 avf[2], bpf[4];
#pragma unroll
    for (int di = 0; di < 2; ++di)
      avf[di] = *(const bf16x8*)&Vsh[(di * 16 + r15) * 64 + (((ks * 4 + c16) ^ r7) << 3)];
#pragma unroll
    for (int mj = 0; mj < 4; ++mj)
      bpf[mj] = *(const bf16x8*)&Psh[(mj * 16 + r15) * 64 + (((ks * 4 + c16) ^ r7) << 3)];
#pragma unroll
    for (int di = 0; di < 2; ++di)
#pragma unroll
      for (int mj = 0; mj < 4; ++mj)
        accc[di][mj] = __builtin_amdgcn_mfma_f32_16x16x32_bf16(avf[di], bpf[mj], accc[di][mj], 0, 0, 0);
  }
  // write ctx[m][h*32+d] into Xs (Cs)
#pragma unroll
  for (int di = 0; di < 2; ++di)
#pragma unroll
    for (int mj = 0; mj < 4; ++mj) {
      union { bf16_t b[4]; uint2 u; } pk;
#pragma unroll
      for (int rg = 0; rg < 4; ++rg) pk.b[rg] = (bf16_t)accc[di][mj][rg];
      int m = mj * 16 + r15;
      *(uint2*)&Xs[m * 256 + (((h * 4 + di * 2 + (c16 >> 1)) ^ (m & 7)) << 3) + ((c16 & 1) << 2)] = pk.u;
    }
  __syncthreads();

  // ---- phase 5: out = ctx @ Wo + bo, per-head column slice ----
  f32x4 acco[4][2];
#pragma unroll
  for (int mi = 0; mi < 4; ++mi)
#pragma unroll
    for (int nj = 0; nj < 2; ++nj) acco[mi][nj] = zero4;

  const bf16_t* wop = woT + (h * 32) * 256;
#pragma unroll
  for (int ks = 0; ks < 8; ++ks) {
    bf16x8 ac[4];
#pragma unroll
    for (int mi = 0; mi < 4; ++mi) {
      int m = mi * 16 + r15;
      ac[mi] = *(const bf16x8*)&Xs[m * 256 + (((ks * 4 + c16) ^ (m & 7)) << 3)];
    }
    bf16x8 bw[2];
#pragma unroll
    for (int nj = 0; nj < 2; ++nj)
      bw[nj] = *(const bf16x8*)&wop[(nj * 16 + r15) * 256 + ks * 32 + c16 * 8];
#pragma unroll
    for (int mi = 0; mi < 4; ++mi)
#pragma unroll
      for (int nj = 0; nj < 2; ++nj)
        acco[mi][nj] = __builtin_amdgcn_mfma_f32_16x16x32_bf16(ac[mi], bw[nj], acco[mi][nj], 0, 0, 0);
  }
  float bof[2];
#pragma unroll
  for (int nj = 0; nj < 2; ++nj) bof[nj] = bo[h * 32 + nj * 16 + r15];
  float* outw = out + (size_t)w * (64 * 256);
#pragma unroll
  for (int mi = 0; mi < 4; ++mi)
#pragma unroll
    for (int nj = 0; nj < 2; ++nj)
#pragma unroll
      for (int rg = 0; rg < 4; ++rg) {
        int m = mi * 16 + c16 * 4 + rg;
        int j = h * 32 + nj * 16 + r15;
        outw[m * 256 + j] = acco[mi][nj][rg] + bof[nj];
      }
}

// ---------------- launcher ----------------

extern "C" void kernel_launch(void* const* d_in, const int* in_sizes, int n_in,
                              void* d_out, int out_size, void* d_ws, size_t ws_size,
                              hipStream_t stream) {
  const float* hidden = (const float*)d_in[0];
  const float* mask = (const float*)d_in[1];
  const float* Wq = (const float*)d_in[2];
  const float* bq = (const float*)d_in[3];
  const float* Wk = (const float*)d_in[4];
  const float* Wv = (const float*)d_in[5];
  const float* bv = (const float*)d_in[6];
  const float* ls = (const float*)d_in[7];
  const float* w1 = (const float*)d_in[8];
  const float* b1 = (const float*)d_in[9];
  const float* w2 = (const float*)d_in[10];
  const float* Wo = (const float*)d_in[11];
  const float* bo = (const float*)d_in[12];
  float* out = (float*)d_out;

  char* ws = (char*)d_ws;
  bf16_t* wqkvT = (bf16_t*)(ws);              // 3*256*256*2 = 393216 B
  bf16_t* woT = (bf16_t*)(ws + 393216);       // 131072 B
  float* rpbT = (float*)(ws + 524288);        // 8*64*64*4 = 131072 B
  float* cbias = (float*)(ws + 655360);       // 225*8*4 = 7200 B

  hipLaunchKernelGGL(prep_weights_k, dim3(1024), dim3(256), 0, stream, Wq, Wk, Wv, Wo, wqkvT, woT);
  hipLaunchKernelGGL(prep_cpb_bias_k, dim3(225), dim3(256), 0, stream, w1, b1, w2, cbias);
  hipLaunchKernelGGL(prep_rpb_k, dim3(128), dim3(256), 0, stream, cbias, rpbT);
  hipLaunchKernelGGL(swin_attn_k, dim3(4096), dim3(512), 0, stream,
                     hidden, mask, bq, bv, ls, bo, wqkvT, woT, rpbT, out);
}